// Round 8
// baseline (281.087 us; speedup 1.0000x reference)
//
#include <hip/hip_runtime.h>
#include <math.h>

#define B_SZ   64
#define T_SZ   512
#define DOBS   128
#define DLAT   16
#define DHID   256
#define K_SZ   8
#define ROWS_A 32768   // B*T

#define LOG2PI_F 1.8378770664093453f
#define VAR_F    5.0e-4f

// ws layout: doubles 0..3 (floats 0..7): recon, logq, msm accumulators (fp64)
#define LINV0_OFF   16
#define LOGDET0_OFF 2064
#define LINVT_OFF   2080
#define LOGDETT_OFF 4128
#define WIMG_F_OFF  8192      // bf16 weight images start here (ushort region)

// bf16 weight image offsets (in shorts, within wimg)
#define EVT_W1   0            // [k][i=256][d pad24]   <- Wt1[k][d][i]
#define EVT_W2   49152        // [k][d2=16][h pad264]  <- Wt2[k][h][d2]
#define EVT_LINV 82944        // [k][i=16][j pad24]    <- LinvT[k][i][j]
#define ENC_W1   86016        // [n=256][kk=128 pad136] <- W1[kk][n]
#define ENC_W2   120832       // [n=32][kk=256 pad264]  <- W2[kk][n]
#define DEC_W1   129280       // [n=256][kk=16 pad24]   <- Wd1[kk][n]
#define DEC_W2   135424       // [n=128][kk=256 pad264] <- Wd2[kk][n]
#define WCVT_TOTAL 141568     // logical (unpadded) element count

#define Z_OUT_OFF   4194304   // B*T*DOBS
#define LOSS_OFF    4718592   // + B*T*DLAT
// staging inside x_hat region of d_out (consumed before dec overwrites):
#define PBUF_OFF  262144
#define ACC_OFF   327680

typedef __attribute__((ext_vector_type(8))) short short8;
typedef __attribute__((ext_vector_type(8))) unsigned short ush8;
typedef __attribute__((ext_vector_type(4))) float floatx4;

__device__ __forceinline__ float leakyf(float v) { return v > 0.f ? v : 0.01f * v; }
__device__ __forceinline__ unsigned short f2bf(float f) {
  union { float f; unsigned int u; } v; v.f = f;
  unsigned int lsb = (v.u >> 16) & 1;
  v.u += 0x7fffu + lsb;   // round-to-nearest-even
  return (unsigned short)(v.u >> 16);
}

// ---------------------------------------------------------------------------
// prep: per-k Cholesky of C C^T + 1e-6 I, then Linv (lower-tri inverse), logdet.
// Job 0 zeroes the fp64 accumulators.
// ---------------------------------------------------------------------------
__global__ __launch_bounds__(256) void prep_kernel(const float* __restrict__ init_cov,
                                                   const float* __restrict__ covs,
                                                   float* __restrict__ ws) {
  __shared__ float M[16][16];
  __shared__ float L[16][16];
  __shared__ float X[16][17];
  int job = blockIdx.x;
  const float* C = (job < 8) ? (init_cov + job * 256) : (covs + (job - 8) * 256);
  float* linv = ws + ((job < 8) ? (LINV0_OFF + job * 256) : (LINVT_OFF + (job - 8) * 256));
  float* logdet = ws + ((job < 8) ? (LOGDET0_OFF + job) : (LOGDETT_OFF + (job - 8)));
  int tid = threadIdx.x;
  if (job == 0 && tid < 8) ws[tid] = 0.f;   // doubles 0..3 = 0.0
  int i = tid >> 4, j = tid & 15;
  {
    float s = (i == j) ? 1e-6f : 0.f;
    #pragma unroll
    for (int p = 0; p < 16; ++p) s += C[i * 16 + p] * C[j * 16 + p];
    M[i][j] = s;
  }
  __syncthreads();
  for (int c = 0; c < 16; ++c) {
    if (tid == 0) {
      float s = M[c][c];
      for (int p = 0; p < c; ++p) s -= L[c][p] * L[c][p];
      L[c][c] = sqrtf(s);
    }
    __syncthreads();
    if (tid > c && tid < 16) {
      float s = M[tid][c];
      for (int p = 0; p < c; ++p) s -= L[tid][p] * L[c][p];
      L[tid][c] = s / L[c][c];
    }
    __syncthreads();
  }
  if (tid < 16) {
    for (int r = 0; r < 16; ++r) {
      float s = (r == tid) ? 1.f : 0.f;
      for (int p = tid; p < r; ++p) s -= L[r][p] * X[p][tid];
      X[r][tid] = (r >= tid) ? s / L[r][r] : 0.f;
    }
  }
  __syncthreads();
  linv[i * 16 + j] = X[i][j];
  if (tid == 0) {
    float s = 0.f;
    for (int d = 0; d < 16; ++d) s += logf(L[d][d]);
    *logdet = 2.f * s;
  }
}

// ---------------------------------------------------------------------------
// wcvt: one-time fp32 -> bf16 weight-image conversion (frag-ready layouts).
// ---------------------------------------------------------------------------
__global__ __launch_bounds__(256) void wcvt_kernel(
    const float* __restrict__ Wt1, const float* __restrict__ Wt2,
    const float* __restrict__ W1, const float* __restrict__ W2,
    const float* __restrict__ Wd1, const float* __restrict__ Wd2,
    const float* __restrict__ ws, unsigned short* __restrict__ wimg) {
  for (int e = blockIdx.x * 256 + threadIdx.x; e < WCVT_TOTAL; e += gridDim.x * 256) {
    if (e < 32768) {                       // EVT_W1
      int k = e >> 12, r = e & 4095, i = r >> 4, d = r & 15;
      wimg[EVT_W1 + k * 6144 + i * 24 + d] = f2bf(Wt1[k * 4096 + d * 256 + i]);
    } else if (e < 65536) {                // EVT_W2
      int e2 = e - 32768; int k = e2 >> 12, r = e2 & 4095, h = r >> 4, d2 = r & 15;
      wimg[EVT_W2 + k * 4224 + d2 * 264 + h] = f2bf(Wt2[k * 4096 + h * 16 + d2]);
    } else if (e < 67584) {                // EVT_LINV
      int e2 = e - 65536; int k = e2 >> 8, r = e2 & 255, i = r >> 4, j = r & 15;
      wimg[EVT_LINV + k * 384 + i * 24 + j] = f2bf(ws[LINVT_OFF + k * 256 + i * 16 + j]);
    } else if (e < 100352) {               // ENC_W1
      int e2 = e - 67584; int n = e2 >> 7, kk = e2 & 127;
      wimg[ENC_W1 + n * 136 + kk] = f2bf(W1[kk * 256 + n]);
    } else if (e < 108544) {               // ENC_W2
      int e2 = e - 100352; int n = e2 >> 8, kk = e2 & 255;
      wimg[ENC_W2 + n * 264 + kk] = f2bf(W2[kk * 32 + n]);
    } else if (e < 112640) {               // DEC_W1
      int e2 = e - 108544; int n = e2 >> 4, kk = e2 & 15;
      wimg[DEC_W1 + n * 24 + kk] = f2bf(Wd1[kk * 256 + n]);
    } else {                               // DEC_W2
      int e2 = e - 112640; int n = e2 & 127, kk = e2 >> 7;
      wimg[DEC_W2 + n * 264 + kk] = f2bf(Wd2[kk * 128 + n]);
    }
  }
}

// ---------------------------------------------------------------------------
// encoder (bf16 MFMA, barrier-free): all W-frags from global bf16 image,
// biases in registers, per-wave LDS transpose tile only. 512 blocks x 64 rows.
// ---------------------------------------------------------------------------
__global__ __launch_bounds__(256) void enc_kernel(
    const float* __restrict__ x, const float* __restrict__ eps,
    const float* __restrict__ b1, const float* __restrict__ b2,
    const unsigned short* __restrict__ wimg,
    float* __restrict__ z_out, float* __restrict__ ws) {
  __shared__ __align__(16) unsigned short ttile[4][16 * 56];
  int tid = threadIdx.x;
  int wid = tid >> 6, lane = tid & 63;
  int m = lane & 15, quad = lane >> 4;
  unsigned short* tt = ttile[wid];
  const unsigned short* w1i = wimg + ENC_W1;
  const unsigned short* w2i = wimg + ENC_W2;
  long rowb = (long)blockIdx.x * 64 + wid * 16;

  float b1r[16];
  #pragma unroll
  for (int c = 0; c < 16; ++c) b1r[c] = b1[c * 16 + m];

  // A-frags from x
  short8 xa[4];
  const float* xp = x + (rowb + m) * 128 + quad * 8;
  #pragma unroll
  for (int kt = 0; kt < 4; ++kt) {
    float4 f0 = *(const float4*)(xp + kt * 32);
    float4 f1 = *(const float4*)(xp + kt * 32 + 4);
    short8 v;
    v[0] = (short)f2bf(f0.x); v[1] = (short)f2bf(f0.y);
    v[2] = (short)f2bf(f0.z); v[3] = (short)f2bf(f0.w);
    v[4] = (short)f2bf(f1.x); v[5] = (short)f2bf(f1.y);
    v[6] = (short)f2bf(f1.z); v[7] = (short)f2bf(f1.w);
    xa[kt] = v;
  }
  float bm0 = b2[m], bm1 = b2[16 + m];
  floatx4 a20 = {bm0, bm0, bm0, bm0};
  floatx4 a21 = {bm1, bm1, bm1, bm1};
  #pragma unroll
  for (int cp = 0; cp < 8; ++cp) {
    #pragma unroll
    for (int h = 0; h < 2; ++h) {
      int c = cp * 2 + h;
      float bias = b1r[c];
      floatx4 a1 = {bias, bias, bias, bias};
      #pragma unroll
      for (int kt = 0; kt < 4; ++kt) {
        short8 bf = *(const short8*)&w1i[(c * 16 + m) * 136 + kt * 32 + quad * 8];
        a1 = __builtin_amdgcn_mfma_f32_16x16x32_bf16(xa[kt], bf, a1, 0, 0, 0);
      }
      #pragma unroll
      for (int g = 0; g < 4; ++g)
        tt[(quad * 4 + g) * 56 + h * 16 + m] = f2bf(leakyf(a1[g]));
    }
    short8 ha = *(const short8*)&tt[m * 56 + quad * 8];
    short8 wb0 = *(const short8*)&w2i[m * 264 + cp * 32 + quad * 8];
    short8 wb1 = *(const short8*)&w2i[(16 + m) * 264 + cp * 32 + quad * 8];
    a20 = __builtin_amdgcn_mfma_f32_16x16x32_bf16(ha, wb0, a20, 0, 0, 0);
    a21 = __builtin_amdgcn_mfma_f32_16x16x32_bf16(ha, wb1, a21, 0, 0, 0);
  }
  // epilogue: z + logq
  float logq_acc = 0.f;
  #pragma unroll
  for (int g = 0; g < 4; ++g) {
    long row = rowb + quad * 4 + g;
    float mu = a20[g], lv = a21[g];
    float ev = eps[row * 16 + m];
    float zv = mu + __expf(0.5f * lv) * ev;
    z_out[row * 16 + m] = zv;
    float zz = zv - mu;
    logq_acc += lv + zz * zz * __expf(-lv);
  }
  #pragma unroll
  for (int off = 1; off < 64; off <<= 1) logq_acc += __shfl_xor(logq_acc, off, 64);
  if (lane == 0) {
    double v = -0.5 * ((double)logq_acc + 16.0 * 16.0 * (double)LOG2PI_F);
    atomicAdd((double*)ws + 1, v);
  }
}

// ---------------------------------------------------------------------------
// evt (bf16 MFMA, barrier-free): per k, 64 rows/block, 16 rows/wave.
// All W-frags read from L2-hot global bf16 image; only per-wave LDS tiles.
// ---------------------------------------------------------------------------
__global__ __launch_bounds__(256) void evt_kernel(
    const float* __restrict__ z, const unsigned short* __restrict__ wimg,
    const float* __restrict__ bt1, const float* __restrict__ bt2,
    const float* __restrict__ ws, float* __restrict__ evT) {
  __shared__ __align__(16) unsigned short ttile[4][16 * 56];
  __shared__ __align__(16) unsigned short dtile[4][16 * 24];
  int tid = threadIdx.x;
  int k = blockIdx.y;
  int wid = tid >> 6, lane = tid & 63;
  int m = lane & 15, quad = lane >> 4;
  unsigned short* tt = ttile[wid];
  unsigned short* db = dtile[wid];
  const unsigned short* w1i = wimg + EVT_W1 + k * 6144;
  const unsigned short* w2i = wimg + EVT_W2 + k * 4224;
  const unsigned short* li  = wimg + EVT_LINV + k * 384;
  float logdetk = ws[LOGDETT_OFF + k];
  float btv = bt2[k * 16 + m];
  float bt1r[16];
  #pragma unroll
  for (int c = 0; c < 16; ++c) bt1r[c] = bt1[k * 256 + c * 16 + m];
  short8 lb = (short8)0;
  if (quad < 2) lb = *(const short8*)&li[m * 24 + quad * 8];

  long rowb = (long)blockIdx.x * 64 + wid * 16;
  short8 za = (short8)0;
  if (quad < 2) {
    const float* zp = z + (rowb + m) * 16 + quad * 8;
    float4 f0 = *(const float4*)zp;
    float4 f1 = *(const float4*)(zp + 4);
    za[0] = (short)f2bf(f0.x); za[1] = (short)f2bf(f0.y);
    za[2] = (short)f2bf(f0.z); za[3] = (short)f2bf(f0.w);
    za[4] = (short)f2bf(f1.x); za[5] = (short)f2bf(f1.y);
    za[6] = (short)f2bf(f1.z); za[7] = (short)f2bf(f1.w);
  }
  floatx4 a2 = {btv, btv, btv, btv};
  #pragma unroll
  for (int cp = 0; cp < 8; ++cp) {
    #pragma unroll
    for (int h = 0; h < 2; ++h) {
      int c = cp * 2 + h;
      short8 bfrag = (short8)0;
      if (quad < 2) bfrag = *(const short8*)&w1i[(c * 16 + m) * 24 + quad * 8];
      float bias = bt1r[c];
      floatx4 a1 = {bias, bias, bias, bias};
      a1 = __builtin_amdgcn_mfma_f32_16x16x32_bf16(za, bfrag, a1, 0, 0, 0);
      #pragma unroll
      for (int g = 0; g < 4; ++g) {
        float v = a1[g];
        float t = __expf(-fabsf(v));
        float sp = fmaxf(v, 0.f) + __logf(1.f + t);
        tt[(quad * 4 + g) * 56 + h * 16 + m] = f2bf(sp);
      }
    }
    short8 ha = *(const short8*)&tt[m * 56 + quad * 8];
    short8 wb = *(const short8*)&w2i[m * 264 + cp * 32 + quad * 8];
    a2 = __builtin_amdgcn_mfma_f32_16x16x32_bf16(ha, wb, a2, 0, 0, 0);
  }
  // diff -> dtile -> GEMM3 vs Linv^T
  #pragma unroll
  for (int g = 0; g < 4; ++g) {
    long grow = rowb + quad * 4 + g;
    float znx = (grow + 1 < ROWS_A) ? z[(grow + 1) * 16 + m] : 0.f;
    db[(quad * 4 + g) * 24 + m] = f2bf(znx - a2[g]);
  }
  short8 da = (short8)0;
  if (quad < 2) da = *(const short8*)&db[m * 24 + quad * 8];
  floatx4 a3 = {0.f, 0.f, 0.f, 0.f};
  a3 = __builtin_amdgcn_mfma_f32_16x16x32_bf16(da, lb, a3, 0, 0, 0);
  #pragma unroll
  for (int g = 0; g < 4; ++g) {
    float v = a3[g];
    v = v * v;
    v += __shfl_xor(v, 1, 64);
    v += __shfl_xor(v, 2, 64);
    v += __shfl_xor(v, 4, 64);
    v += __shfl_xor(v, 8, 64);
    long grow = rowb + quad * 4 + g;
    if (m == 0 && (grow & 511) != 511) {
      long r1 = grow + 1;
      evT[(r1 >> 9) * 4096 + (long)k * 512 + (r1 & 511)] =
          -0.5f * (16.f * LOG2PI_F + logdetk + v);
    }
  }
}

// ---------------------------------------------------------------------------
// HMM forward as a parallel scan over 8x8 transition matrices (see r5 notes).
// ---------------------------------------------------------------------------
__global__ __launch_bounds__(256) void hmm_scan(const float* __restrict__ Q,
                                                const float* __restrict__ evT,
                                                float* __restrict__ pbuf,
                                                float* __restrict__ accbuf) {
  int tid = threadIdx.x;
  int wid = tid >> 6, lane = tid & 63;
  int job = blockIdx.x * 4 + wid;
  int b = job >> 4, c = job & 15;
  int i = lane >> 3, j = lane & 7;

  float qp[8];
  #pragma unroll
  for (int p = 0; p < 8; ++p) {
    float mr = Q[p * 8 + 0];
    #pragma unroll
    for (int cc = 1; cc < 8; ++cc) mr = fmaxf(mr, Q[p * 8 + cc]);
    float rs = 0.f;
    #pragma unroll
    for (int cc = 0; cc < 8; ++cc) rs += __expf(Q[p * 8 + cc] - mr);
    qp[p] = __expf(Q[p * 8 + i] - mr) / rs;
  }
  float qself;
  {
    float mr = Q[j * 8 + 0];
    #pragma unroll
    for (int cc = 1; cc < 8; ++cc) mr = fmaxf(mr, Q[j * 8 + cc]);
    float rs = 0.f;
    #pragma unroll
    for (int cc = 0; cc < 8; ++cc) rs += __expf(Q[j * 8 + cc] - mr);
    qself = __expf(Q[j * 8 + i] - mr) / rs;
  }

  int t0 = 1 + c * 32;
  int L = (c == 15) ? 31 : 32;
  const float* evI = evT + (long)b * 4096 + (long)i * 512 + t0;

  float f[32];
  float accm = 0.f;
  #pragma unroll
  for (int s = 0; s < 32; ++s) {
    float e = (s < L) ? evI[s] : 0.f;
    float m = e;
    m = fmaxf(m, __shfl_xor(m, 8, 64));
    m = fmaxf(m, __shfl_xor(m, 16, 64));
    m = fmaxf(m, __shfl_xor(m, 32, 64));
    f[s] = __expf(e - m);
    if (s < L) accm += m;
  }

  float P = f[0] * qself;
  #pragma unroll
  for (int s = 1; s < 32; ++s) {
    if (s < L) {
      float a0 = __shfl(P, j,      64);
      float a1 = __shfl(P, 8 + j,  64);
      float a2 = __shfl(P, 16 + j, 64);
      float a3 = __shfl(P, 24 + j, 64);
      float a4 = __shfl(P, 32 + j, 64);
      float a5 = __shfl(P, 40 + j, 64);
      float a6 = __shfl(P, 48 + j, 64);
      float a7 = __shfl(P, 56 + j, 64);
      float sv = ((qp[0] * a0 + qp[1] * a1) + (qp[2] * a2 + qp[3] * a3))
               + ((qp[4] * a4 + qp[5] * a5) + (qp[6] * a6 + qp[7] * a7));
      P = f[s] * sv;
    }
    if ((s & 7) == 7) {
      float mx = P;
      mx = fmaxf(mx, __shfl_xor(mx, 1, 64));
      mx = fmaxf(mx, __shfl_xor(mx, 2, 64));
      mx = fmaxf(mx, __shfl_xor(mx, 4, 64));
      mx = fmaxf(mx, __shfl_xor(mx, 8, 64));
      mx = fmaxf(mx, __shfl_xor(mx, 16, 64));
      mx = fmaxf(mx, __shfl_xor(mx, 32, 64));
      mx = fmaxf(mx, 1e-30f);
      P = P / mx;
      accm += __logf(mx);
    }
  }
  pbuf[(long)job * 64 + lane] = P;
  if (lane == 0) accbuf[job] = accm;
}

// ---------------------------------------------------------------------------
// Stage 2: fold chunks; ev0 (t=0 mvn) computed inline. One wave per batch.
// ---------------------------------------------------------------------------
__global__ __launch_bounds__(512) void hmm_comb(const float* __restrict__ pi,
                                                const float* __restrict__ z,
                                                const float* __restrict__ init_mean,
                                                const float* __restrict__ pbuf,
                                                const float* __restrict__ accbuf,
                                                float* __restrict__ ws) {
  int tid = threadIdx.x;
  int wid = tid >> 6, lane = tid & 63;
  int b = blockIdx.x * 8 + wid;
  int j = lane & 7;

  float mp = pi[0];
  #pragma unroll
  for (int cc = 1; cc < 8; ++cc) mp = fmaxf(mp, pi[cc]);
  float sp = 0.f;
  #pragma unroll
  for (int cc = 0; cc < 8; ++cc) sp += __expf(pi[cc] - mp);
  float lpi = pi[j] - mp - __logf(sp);

  // ev0(b, k=j) inline
  const float* zr = z + (long)b * 8192;
  const float* linv = ws + LINV0_OFF + j * 256;
  float diff[16];
  #pragma unroll
  for (int d = 0; d < 16; ++d) diff[d] = zr[d] - init_mean[j * 16 + d];
  float quad0 = 0.f;
  #pragma unroll
  for (int i2 = 0; i2 < 16; ++i2) {
    float s = 0.f;
    #pragma unroll
    for (int jj = 0; jj < 16; ++jj) s += linv[i2 * 16 + jj] * diff[jj];
    quad0 += s * s;
  }
  float ev0 = -0.5f * (16.f * LOG2PI_F + ws[LOGDET0_OFF + j] + quad0);

  float lp0 = ev0 + lpi;
  float m0 = lp0;
  m0 = fmaxf(m0, __shfl_xor(m0, 1, 64));
  m0 = fmaxf(m0, __shfl_xor(m0, 2, 64));
  m0 = fmaxf(m0, __shfl_xor(m0, 4, 64));
  float u = __expf(lp0 - m0);
  double acc = (double)m0;

  #pragma unroll
  for (int c = 0; c < 16; ++c) {
    float P = pbuf[((long)b * 16 + c) * 64 + lane];
    float contrib = P * u;
    contrib += __shfl_xor(contrib, 1, 64);
    contrib += __shfl_xor(contrib, 2, 64);
    contrib += __shfl_xor(contrib, 4, 64);
    u = __shfl(contrib, j * 9, 64);
    float mxu = u;
    mxu = fmaxf(mxu, __shfl_xor(mxu, 1, 64));
    mxu = fmaxf(mxu, __shfl_xor(mxu, 2, 64));
    mxu = fmaxf(mxu, __shfl_xor(mxu, 4, 64));
    mxu = fmaxf(mxu, 1e-30f);
    u = u / mxu;
    acc += (double)(__logf(mxu) + accbuf[b * 16 + c]);
  }
  float su = u;
  su += __shfl_xor(su, 1, 64);
  su += __shfl_xor(su, 2, 64);
  su += __shfl_xor(su, 4, 64);
  double logZ = acc + (double)__logf(su);
  if (lane == 0) atomicAdd((double*)ws + 2, logZ);
}

// ---------------------------------------------------------------------------
// decoder (bf16 MFMA, barrier-free): all W-frags from global image,
// biases in registers, per-wave LDS tile only. 512 blocks x 64 rows.
// ---------------------------------------------------------------------------
__global__ __launch_bounds__(256) void dec_kernel(
    const float* __restrict__ x, const float* __restrict__ z,
    const float* __restrict__ bd1, const float* __restrict__ bd2,
    const unsigned short* __restrict__ wimg,
    float* __restrict__ xhat, float* __restrict__ ws) {
  __shared__ __align__(16) unsigned short ttile[4][16 * 56];
  int tid = threadIdx.x;
  int wid = tid >> 6, lane = tid & 63;
  int m = lane & 15, quad = lane >> 4;
  unsigned short* tt = ttile[wid];
  const unsigned short* w1i = wimg + DEC_W1;
  const unsigned short* w2i = wimg + DEC_W2;
  long rowb = (long)blockIdx.x * 64 + wid * 16;

  float bd1r[16];
  #pragma unroll
  for (int c = 0; c < 16; ++c) bd1r[c] = bd1[c * 16 + m];

  short8 za = (short8)0;
  if (quad < 2) {
    const float* zp = z + (rowb + m) * 16 + quad * 8;
    float4 f0 = *(const float4*)zp;
    float4 f1 = *(const float4*)(zp + 4);
    za[0] = (short)f2bf(f0.x); za[1] = (short)f2bf(f0.y);
    za[2] = (short)f2bf(f0.z); za[3] = (short)f2bf(f0.w);
    za[4] = (short)f2bf(f1.x); za[5] = (short)f2bf(f1.y);
    za[6] = (short)f2bf(f1.z); za[7] = (short)f2bf(f1.w);
  }
  floatx4 a2[8];
  #pragma unroll
  for (int c2 = 0; c2 < 8; ++c2) {
    float bv = bd2[c2 * 16 + m];
    a2[c2] = (floatx4){bv, bv, bv, bv};
  }
  #pragma unroll
  for (int cp = 0; cp < 8; ++cp) {
    #pragma unroll
    for (int h = 0; h < 2; ++h) {
      int c = cp * 2 + h;
      short8 bfrag = (short8)0;
      if (quad < 2) bfrag = *(const short8*)&w1i[(c * 16 + m) * 24 + quad * 8];
      float bias = bd1r[c];
      floatx4 a1 = {bias, bias, bias, bias};
      a1 = __builtin_amdgcn_mfma_f32_16x16x32_bf16(za, bfrag, a1, 0, 0, 0);
      #pragma unroll
      for (int g = 0; g < 4; ++g)
        tt[(quad * 4 + g) * 56 + h * 16 + m] = f2bf(leakyf(a1[g]));
    }
    short8 ha = *(const short8*)&tt[m * 56 + quad * 8];
    #pragma unroll
    for (int c2 = 0; c2 < 8; ++c2) {
      short8 wb = *(const short8*)&w2i[(c2 * 16 + m) * 264 + cp * 32 + quad * 8];
      a2[c2] = __builtin_amdgcn_mfma_f32_16x16x32_bf16(ha, wb, a2[c2], 0, 0, 0);
    }
  }
  const float C0 = -0.5f * logf(6.2831853071795864f * VAR_F);
  float rsum = 0.f;
  #pragma unroll
  for (int c2 = 0; c2 < 8; ++c2) {
    int col = c2 * 16 + m;
    #pragma unroll
    for (int g = 0; g < 4; ++g) {
      long row = rowb + quad * 4 + g;
      float xh = a2[c2][g];
      xhat[row * 128 + col] = xh;
      float dd = x[row * 128 + col] - xh;
      rsum += C0 - dd * dd * (0.5f / VAR_F);
    }
  }
  #pragma unroll
  for (int off = 1; off < 64; off <<= 1) rsum += __shfl_xor(rsum, off, 64);
  if (lane == 0) atomicAdd((double*)ws + 0, (double)rsum);
}

__global__ void fin_kernel(const float* __restrict__ ws, float* __restrict__ out) {
  const double* dws = (const double*)ws;
  double loss = -((dws[0] - dws[1] + dws[2]) * (1.0 / 64.0));
  out[LOSS_OFF] = (float)loss;
}

extern "C" void kernel_launch(void* const* d_in, const int* in_sizes, int n_in,
                              void* d_out, int out_size, void* d_ws, size_t ws_size,
                              hipStream_t stream) {
  (void)in_sizes; (void)n_in; (void)out_size; (void)ws_size;
  const float* x   = (const float*)d_in[0];
  const float* eps = (const float*)d_in[1];
  const float* W1  = (const float*)d_in[2];
  const float* b1  = (const float*)d_in[3];
  const float* W2  = (const float*)d_in[4];
  const float* b2  = (const float*)d_in[5];
  const float* Wt1 = (const float*)d_in[6];
  const float* bt1 = (const float*)d_in[7];
  const float* Wt2 = (const float*)d_in[8];
  const float* bt2 = (const float*)d_in[9];
  const float* Wd1 = (const float*)d_in[10];
  const float* bd1 = (const float*)d_in[11];
  const float* Wd2 = (const float*)d_in[12];
  const float* bd2 = (const float*)d_in[13];
  const float* Q   = (const float*)d_in[14];
  const float* pi  = (const float*)d_in[15];
  const float* im  = (const float*)d_in[16];
  const float* ic  = (const float*)d_in[17];
  const float* cv  = (const float*)d_in[18];
  float* out = (float*)d_out;
  float* ws  = (float*)d_ws;
  float* z_out = out + Z_OUT_OFF;
  float* evT  = out;             // staged in x_hat region, consumed before dec
  float* pbuf = out + PBUF_OFF;
  float* accb = out + ACC_OFF;
  unsigned short* wimg = (unsigned short*)(ws + WIMG_F_OFF);

  prep_kernel<<<16, 256, 0, stream>>>(ic, cv, ws);
  wcvt_kernel<<<144, 256, 0, stream>>>(Wt1, Wt2, W1, W2, Wd1, Wd2, ws, wimg);
  enc_kernel<<<512, 256, 0, stream>>>(x, eps, b1, b2, wimg, z_out, ws);
  evt_kernel<<<dim3(512, 8), 256, 0, stream>>>(z_out, wimg, bt1, bt2, ws, evT);
  hmm_scan<<<256, 256, 0, stream>>>(Q, evT, pbuf, accb);
  hmm_comb<<<8, 512, 0, stream>>>(pi, z_out, im, pbuf, accb, ws);
  dec_kernel<<<512, 256, 0, stream>>>(x, z_out, bd1, bd2, wimg, out, ws);
  fin_kernel<<<1, 1, 0, stream>>>(ws, out);
}